// Round 2
// baseline (429.930 us; speedup 1.0000x reference)
//
#include <hip/hip_runtime.h>
#include <math.h>

// ArmInt: per-row integerized MLP, B rows x 32 features.
//
// R1 post-mortem: __launch_bounds__(256,4) capped regs at 128/wave; the
// allocator kept only 36 arch VGPRs and spilled h[32]/hn[32] to AGPRs.
// Each spilled read is a v_accvgpr_read (VALU) -> ~2.4x VALU inst inflation
// (measured 164us vs 56us pure-FMA floor @ 85% VALUBusy, VGPR_Count=36).
// Fix: request >=2 waves/EU (256-reg cap) so the ~80-float live set stays in
// arch VGPRs. Occupancy drops but 32 independent FMA accumulator chains give
// ample ILP to keep the SIMD issue port saturated.

__global__ __launch_bounds__(256)
__attribute__((amdgpu_waves_per_eu(2)))
void armint_kernel(const float* __restrict__ x,
                   const float* __restrict__ w0, const float* __restrict__ b0,
                   const float* __restrict__ w1, const float* __restrict__ b1,
                   const float* __restrict__ wo, const float* __restrict__ bo,
                   float* __restrict__ out, int n)
{
    int r = blockIdx.x * blockDim.x + threadIdx.x;
    if (r >= n) return;

    const float4* xr = (const float4*)(x + (size_t)r * 32);
    float h[32];
    float hn[32];

    #pragma unroll
    for (int q = 0; q < 8; ++q) {
        float4 v = xr[q];
        h[4*q+0] = v.x * 256.0f;
        h[4*q+1] = v.y * 256.0f;
        h[4*q+2] = v.z * 256.0f;
        h[4*q+3] = v.w * 256.0f;
    }

    // layer 0 (residual + relu). Bias folded into acc init (ulp-level order
    // shift only; layer-0 already differs from np's pairwise order and sits
    // 1 quant step under a 6.5-step threshold).
    #pragma unroll
    for (int i = 0; i < 32; ++i) {
        float acc = b0[i];
        #pragma unroll
        for (int j = 0; j < 32; ++j)
            acc = fmaf(h[j], w0[i*32+j], acc);
        acc = fmaf(h[i], 256.0f, acc);   // residual; *256 exact (pow2)
        // relu(trunc((xx+sign(xx)*128)/256)) == max(trunc((xx+128)/256), 0)
        hn[i] = fmaxf(truncf((acc + 128.0f) * (1.0f/256.0f)), 0.0f);
    }

    // layer 1 (residual + relu) — integer-valued fp32, exact in any order
    #pragma unroll
    for (int i = 0; i < 32; ++i) {
        float acc = b1[i];
        #pragma unroll
        for (int j = 0; j < 32; ++j)
            acc = fmaf(hn[j], w1[i*32+j], acc);
        acc = fmaf(hn[i], 256.0f, acc);
        h[i] = fmaxf(truncf((acc + 128.0f) * (1.0f/256.0f)), 0.0f);
    }

    // output layer (no residual, no relu) — true sign-away rounding
    float o[2];
    #pragma unroll
    for (int i = 0; i < 2; ++i) {
        float acc = bo[i];
        #pragma unroll
        for (int j = 0; j < 32; ++j)
            acc = fmaf(h[j], wo[i*32+j], acc);
        float adj = acc + copysignf(128.0f, acc);
        o[i] = truncf(adj * (1.0f/256.0f)) * (1.0f/256.0f);
    }

    float mu = o[0];
    float ls = o[1];
    float cl = fminf(fmaxf(ls - 4.0f, -4.6f), 5.0f);
    float sc = expf(cl);

    size_t nn = (size_t)n;
    out[r]        = mu;
    out[nn + r]   = sc;
    out[2*nn + r] = ls;
}

extern "C" void kernel_launch(void* const* d_in, const int* in_sizes, int n_in,
                              void* d_out, int out_size, void* d_ws, size_t ws_size,
                              hipStream_t stream) {
    const float* x  = (const float*)d_in[0];
    const float* w0 = (const float*)d_in[1];
    const float* b0 = (const float*)d_in[2];
    const float* w1 = (const float*)d_in[3];
    const float* b1 = (const float*)d_in[4];
    const float* wo = (const float*)d_in[5];
    const float* bo = (const float*)d_in[6];
    float* out = (float*)d_out;

    int n = in_sizes[0] / 32;           // rows (B = 2097152)
    int block = 256;
    int grid = (n + block - 1) / block;

    armint_kernel<<<grid, block, 0, stream>>>(x, w0, b0, w1, b1, wo, bo, out, n);
}

// Round 3
// 418.446 us; speedup vs baseline: 1.0274x; 1.0274x over previous
//
#include <hip/hip_runtime.h>
#include <math.h>

// ArmInt via MFMA (bf16 exact-split), 32 rows per wave.
//
// R2 post-mortem: the VALU kernel is stuck at 171us because the backend keeps
// arch-VGPRs at 36 and shuffles h[32]/hn[32] through AGPRs (v_accvgpr_* are
// VALU insts -> 2.5x inflation over the 56us pure-FMA floor); waves_per_eu
// attrs don't change it. Structural fix: move the dot products to MFMA
// (16x16x32 bf16), where AGPR accumulators are native.
//
// Exactness: fp32 value = sum of 3 bf16 chunks (hi/mid/lo 8 mantissa bits),
// split exact via bit-truncation + exact fp32 subtraction. Weights/biases are
// integerized: W entries are small ints (exact in 1 bf16 chunk); post-layer-0
// activations are ints < 2^16 (exact in 2 chunks). Layer-0 h=256*x needs the
// full 3 chunks. Products bf16*bf16 are exact in fp32; only fp32 accumulation
// order differs from the reference (same as the passing R1 kernel, which sat
// at 1 quantum vs a 6.5-quantum threshold).
//
// Layout: MFMA A-frag lane holds A[m=lane&15][k=(lane>>4)*8+j]; B-frag holds
// B[k][n=lane&15] = W[n][k] (W is row-major, K-contiguous -> direct load);
// C/D: col=lane&15, row=(lane>>4)*4+reg. Between layers the C-layout output
// must become A-layout input -> round-trip through wave-private LDS (stride
// 36 floats: 16B-aligned b128 A-reads, only free 2-way bank aliasing).
// Residual h is staged in the same LDS tile and read back in C-layout.
// All LDS deps are intra-wave (lockstep + in-order DS) -> no __syncthreads.

typedef __attribute__((ext_vector_type(8))) short bf16x8;
typedef __attribute__((ext_vector_type(4))) float f32x4;

#define MFMA16(A, B, C) __builtin_amdgcn_mfma_f32_16x16x32_bf16((A), (B), (C), 0, 0, 0)

__device__ inline short bf_top(float v) {              // top bf16 chunk (bit-trunc)
    return (short)(__float_as_uint(v) >> 16);
}
__device__ inline float bf_topf(float v) {             // same chunk as fp32
    return __uint_as_float(__float_as_uint(v) & 0xffff0000u);
}

__global__ __launch_bounds__(256)
void armint_mfma(const float* __restrict__ x,
                 const float* __restrict__ w0, const float* __restrict__ b0,
                 const float* __restrict__ w1, const float* __restrict__ b1,
                 const float* __restrict__ wo, const float* __restrict__ bo,
                 float* __restrict__ out, int nrows)
{
    __shared__ float lds_all[4][32 * 36];

    const int lane = threadIdx.x & 63;
    const int wave = threadIdx.x >> 6;
    const int lm   = lane & 15;      // A-row / B-col / C-col index
    const int quad = lane >> 4;      // 0..3
    float* lds = lds_all[wave];

    const size_t nn = (size_t)nrows;
    const size_t rowbase = (size_t)blockIdx.x * 128 + (size_t)wave * 32;

    // ---------------- weight/bias fragments (exact bf16) ----------------
    bf16x8 w0f[2], w1f[2], wof;
    float b0v[2], b1v[2], bov;
    #pragma unroll
    for (int hh = 0; hh < 2; ++hh) {
        const int n = lm + 16 * hh;
        const float* p0 = w0 + n * 32 + quad * 8;
        const float* p1 = w1 + n * 32 + quad * 8;
        #pragma unroll
        for (int j = 0; j < 8; ++j) {
            w0f[hh][j] = bf_top(p0[j]);
            w1f[hh][j] = bf_top(p1[j]);
        }
        b0v[hh] = b0[n] + 128.0f;    // fold the +128 half-away rounding offset
        b1v[hh] = b1[n] + 128.0f;
    }
    #pragma unroll
    for (int j = 0; j < 8; ++j)
        wof[j] = (lm < 2) ? bf_top(wo[lm * 32 + quad * 8 + j]) : (short)0;
    bov = (lm < 2) ? bo[lm] : 0.0f;  // no +128: output layer needs signed rounding

    // ---------------- load x, stage h=256x, exact 3-chunk split ----------------
    bf16x8 a0[2], a1[2], a2[2];
    #pragma unroll
    for (int t = 0; t < 2; ++t) {
        const float* xp = x + (rowbase + (size_t)(t * 16 + lm)) * 32 + quad * 8;
        float4 v0 = *(const float4*)xp;
        float4 v1 = *(const float4*)(xp + 4);
        float h[8] = {v0.x, v0.y, v0.z, v0.w, v1.x, v1.y, v1.z, v1.w};
        #pragma unroll
        for (int j = 0; j < 8; ++j) h[j] *= 256.0f;

        const int base = (t * 16 + lm) * 36 + quad * 8;
        *(float4*)&lds[base]     = make_float4(h[0], h[1], h[2], h[3]);
        *(float4*)&lds[base + 4] = make_float4(h[4], h[5], h[6], h[7]);

        #pragma unroll
        for (int j = 0; j < 8; ++j) {
            float c0 = bf_topf(h[j]);
            a0[t][j] = bf_top(h[j]);
            float r1 = h[j] - c0;                 // exact
            float c1 = bf_topf(r1);
            a1[t][j] = bf_top(r1);
            float r2 = r1 - c1;                   // exact, fits one bf16
            a2[t][j] = bf_top(r2);
        }
    }

    // ---------------- layer 0: MFMA + residual/round/relu epilogue ----------------
    f32x4 acc[2][2];
    #pragma unroll
    for (int t = 0; t < 2; ++t)
        #pragma unroll
        for (int hh = 0; hh < 2; ++hh) {
            f32x4 c = {b0v[hh], b0v[hh], b0v[hh], b0v[hh]};
            c = MFMA16(a0[t], w0f[hh], c);
            c = MFMA16(a1[t], w0f[hh], c);
            c = MFMA16(a2[t], w0f[hh], c);
            acc[t][hh] = c;
        }
    #pragma unroll
    for (int t = 0; t < 2; ++t)
        #pragma unroll
        for (int hh = 0; hh < 2; ++hh)
            #pragma unroll
            for (int k = 0; k < 4; ++k) {
                const int idx = (t * 16 + quad * 4 + k) * 36 + lm + 16 * hh;
                float hres = lds[idx];                       // staged h (C-layout read)
                float xx = fmaf(hres, 256.0f, acc[t][hh][k]); // + residual
                lds[idx] = fmaxf(truncf(xx * (1.0f / 256.0f)), 0.0f);
            }

    // ---------------- layer 1: reload A-layout, 2-chunk split, MFMA ----------------
    bf16x8 c0f[2], c1f[2];
    #pragma unroll
    for (int t = 0; t < 2; ++t) {
        const int base = (t * 16 + lm) * 36 + quad * 8;
        float4 v0 = *(float4*)&lds[base];
        float4 v1 = *(float4*)&lds[base + 4];
        float h[8] = {v0.x, v0.y, v0.z, v0.w, v1.x, v1.y, v1.z, v1.w};
        #pragma unroll
        for (int j = 0; j < 8; ++j) {
            float c0 = bf_topf(h[j]);
            c0f[t][j] = bf_top(h[j]);
            c1f[t][j] = bf_top(h[j] - c0);        // exact (int < 2^8 residue)
        }
    }
    #pragma unroll
    for (int t = 0; t < 2; ++t)
        #pragma unroll
        for (int hh = 0; hh < 2; ++hh) {
            f32x4 c = {b1v[hh], b1v[hh], b1v[hh], b1v[hh]};
            c = MFMA16(c0f[t], w1f[hh], c);
            c = MFMA16(c1f[t], w1f[hh], c);
            acc[t][hh] = c;
        }
    #pragma unroll
    for (int t = 0; t < 2; ++t)
        #pragma unroll
        for (int hh = 0; hh < 2; ++hh)
            #pragma unroll
            for (int k = 0; k < 4; ++k) {
                const int idx = (t * 16 + quad * 4 + k) * 36 + lm + 16 * hh;
                float hres = lds[idx];                       // hn from layer 0
                float xx = fmaf(hres, 256.0f, acc[t][hh][k]);
                lds[idx] = fmaxf(truncf(xx * (1.0f / 256.0f)), 0.0f);
            }

    // ---------------- output layer ----------------
    bf16x8 d0f[2], d1f[2];
    #pragma unroll
    for (int t = 0; t < 2; ++t) {
        const int base = (t * 16 + lm) * 36 + quad * 8;
        float4 v0 = *(float4*)&lds[base];
        float4 v1 = *(float4*)&lds[base + 4];
        float h[8] = {v0.x, v0.y, v0.z, v0.w, v1.x, v1.y, v1.z, v1.w};
        #pragma unroll
        for (int j = 0; j < 8; ++j) {
            float c0 = bf_topf(h[j]);
            d0f[t][j] = bf_top(h[j]);
            d1f[t][j] = bf_top(h[j] - c0);
        }
    }
    #pragma unroll
    for (int t = 0; t < 2; ++t) {
        f32x4 c = {bov, bov, bov, bov};
        c = MFMA16(d0f[t], wof, c);
        c = MFMA16(d1f[t], wof, c);

        float o[4];
        #pragma unroll
        for (int k = 0; k < 4; ++k) {
            float a = c[k];
            float adj = a + copysignf(128.0f, a);            // signed half-away rounding
            o[k] = truncf(adj * (1.0f / 256.0f)) * (1.0f / 256.0f);
        }
        const size_t row = rowbase + (size_t)(t * 16 + quad * 4);
        if (lm == 0) {                                        // mu
            *(float4*)(out + row) = make_float4(o[0], o[1], o[2], o[3]);
        }
        if (lm == 1) {                                        // log_scale + scale
            *(float4*)(out + 2 * nn + row) = make_float4(o[0], o[1], o[2], o[3]);
            float s[4];
            #pragma unroll
            for (int k = 0; k < 4; ++k)
                s[k] = expf(fminf(fmaxf(o[k] - 4.0f, -4.6f), 5.0f));
            *(float4*)(out + nn + row) = make_float4(s[0], s[1], s[2], s[3]);
        }
    }
}

extern "C" void kernel_launch(void* const* d_in, const int* in_sizes, int n_in,
                              void* d_out, int out_size, void* d_ws, size_t ws_size,
                              hipStream_t stream) {
    const float* x  = (const float*)d_in[0];
    const float* w0 = (const float*)d_in[1];
    const float* b0 = (const float*)d_in[2];
    const float* w1 = (const float*)d_in[3];
    const float* b1 = (const float*)d_in[4];
    const float* wo = (const float*)d_in[5];
    const float* bo = (const float*)d_in[6];
    float* out = (float*)d_out;

    int nrows = in_sizes[0] / 32;             // B = 2097152, multiple of 128
    int grid = nrows / 128;                   // 128 rows per 256-thread block (4 waves x 32)

    armint_mfma<<<grid, 256, 0, stream>>>(x, w0, b0, w1, b1, wo, bo, out, nrows);
}

// Round 4
// 372.350 us; speedup vs baseline: 1.1546x; 1.1238x over previous
//
#include <hip/hip_runtime.h>
#include <math.h>

// ArmInt via MFMA (bf16 exact-split), 32 rows/wave, residual folded into W.
//
// R3 post-mortem: MFMA kernel ~150-160us, still VALU/DS-glue bound
// (~380 VALU + ~76 DS insts/lane; MFMA pipe only ~120cyc/wave). R4 cuts glue:
//  (a) W0'=W0+256I, W1'=W1+256I: residual comes out of the MFMA itself ->
//      epilogue loses the staged-h ds_read + fmac per element.
//  (b) scale folding: compute on x (not 256x) with acc init (b0+128)/256;
//      W1s=(W1+256I)/256, Wos=Wout/256, biases pre-scaled. Epilogue is just
//      max(trunc(acc),0). Layers 1/out are EXACT (all terms are multiples of
//      2^-8, magnitudes < 2^19 -> fp32-exact); layer 0 has the same ulp-order
//      noise as the passing R1/R3 kernels (absmax = 1 quantum vs 6.5 allowed).
//      Only approximation: dropped a2 x W0_lo term (<=0.02 pre-round vs
//      half-width 128 -> ~0.006% flip rate, <=1-2 quanta downstream).
//  (c) weight bf16-chunk split + bias scaling hoisted into a one-block prep
//      kernel writing d_ws (rerun every call; d_ws is re-poisoned each iter).
//
// MFMA 16x16x32 layouts (verified by passing R3):
//   A: lane holds A[m=lane&15][k=(lane>>4)*8+j]
//   B: lane holds B[k=(lane>>4)*8+j][n=lane&15]  (= W[n][k], K-contiguous)
//   C/D: col=lane&15, row=(lane>>4)*4+reg
// Layer-to-layer C->A transform via wave-private LDS (stride 36: 16B-aligned
// b128 reads, only free 2-way bank aliasing). All LDS deps intra-wave ->
// no __syncthreads.

typedef __attribute__((ext_vector_type(8))) short bf16x8;
typedef __attribute__((ext_vector_type(4))) float f32x4;

#define MFMA16(A, B, C) __builtin_amdgcn_mfma_f32_16x16x32_bf16((A), (B), (C), 0, 0, 0)

__device__ inline short bf_top(float v) {              // top bf16 chunk (bit-trunc)
    return (short)(__float_as_uint(v) >> 16);
}
__device__ inline float bf_topf(float v) {             // same chunk as fp32
    return __uint_as_float(__float_as_uint(v) & 0xffff0000u);
}

// d_ws layout:
//   shorts: [0)    w0' hi[32][32]   [1024) w0' lo
//           [2048) w1s hi           [3072) w1s lo
//           [4096) wos  [32][32] (rows >=2 zero)
//   floats at byte 10240: bs0[32], bs1[32], bso[32] (entries >=2 zero)

__global__ void armint_prep(const float* __restrict__ w0, const float* __restrict__ b0,
                            const float* __restrict__ w1, const float* __restrict__ b1,
                            const float* __restrict__ wo, const float* __restrict__ bo,
                            short* __restrict__ ws, float* __restrict__ bsf)
{
    int t = threadIdx.x;
    for (int i = t; i < 1024; i += 256) {
        int n = i >> 5, k = i & 31;
        float diag = (n == k) ? 256.0f : 0.0f;

        float a = w0[i] + diag;                       // W0' (unscaled)
        float ahi = bf_topf(a);
        ws[i]          = bf_top(a);
        ws[1024 + i]   = bf_top(a - ahi);             // exact int residue

        float b = (w1[i] + diag) * (1.0f / 256.0f);   // W1s (scaled, exact pow2)
        float bhi = bf_topf(b);
        ws[2048 + i]   = bf_top(b);
        ws[3072 + i]   = bf_top(b - bhi);

        float c = (n < 2) ? wo[n * 32 + k] * (1.0f / 256.0f) : 0.0f;
        ws[4096 + i]   = bf_top(c);                   // small ints/256: 1 chunk exact
    }
    if (t < 32) {
        bsf[t]      = (b0[t] + 128.0f) * (1.0f / 256.0f);
        bsf[32 + t] = (b1[t] + 128.0f) * (1.0f / 256.0f);
        bsf[64 + t] = (t < 2) ? bo[t] * (1.0f / 256.0f) : 0.0f;
    }
}

__global__ __launch_bounds__(256)
void armint_mfma(const float* __restrict__ x, const short* __restrict__ ws,
                 const float* __restrict__ bias, float* __restrict__ out, int nrows)
{
    __shared__ float lds_all[4][32 * 36];

    const int lane = threadIdx.x & 63;
    const int wave = threadIdx.x >> 6;
    const int lm   = lane & 15;
    const int quad = lane >> 4;
    float* lds = lds_all[wave];

    const size_t nn = (size_t)nrows;
    const size_t rowbase = (size_t)blockIdx.x * 128 + (size_t)wave * 32;

    // ---------------- preprocessed weight/bias fragments ----------------
    bf16x8 w0hi[2], w0lo[2], w1hi[2], w1lo[2], wof;
    float bs0[2], bs1[2];
    #pragma unroll
    for (int hh = 0; hh < 2; ++hh) {
        const int n = lm + 16 * hh;
        const int o = n * 32 + quad * 8;
        w0hi[hh] = *(const bf16x8*)(ws + o);
        w0lo[hh] = *(const bf16x8*)(ws + 1024 + o);
        w1hi[hh] = *(const bf16x8*)(ws + 2048 + o);
        w1lo[hh] = *(const bf16x8*)(ws + 3072 + o);
        bs0[hh] = bias[n];
        bs1[hh] = bias[32 + n];
    }
    wof = *(const bf16x8*)(ws + 4096 + lm * 32 + quad * 8);
    const float bsov = bias[64 + lm];

    // ---------------- load x, exact 3-chunk split (no *256: folded) ----------------
    bf16x8 a0[2], a1[2], a2[2];
    #pragma unroll
    for (int t = 0; t < 2; ++t) {
        const float* xp = x + (rowbase + (size_t)(t * 16 + lm)) * 32 + quad * 8;
        float4 v0 = *(const float4*)xp;
        float4 v1 = *(const float4*)(xp + 4);
        float h[8] = {v0.x, v0.y, v0.z, v0.w, v1.x, v1.y, v1.z, v1.w};
        #pragma unroll
        for (int j = 0; j < 8; ++j) {
            float c0 = bf_topf(h[j]);
            a0[t][j] = bf_top(h[j]);
            float r1 = h[j] - c0;                 // exact
            float c1 = bf_topf(r1);
            a1[t][j] = bf_top(r1);
            a2[t][j] = bf_top(r1 - c1);           // exact, fits one bf16
        }
    }

    // ---------------- layer 0: residual via W' diagonal ----------------
    f32x4 acc[2][2];
    #pragma unroll
    for (int t = 0; t < 2; ++t)
        #pragma unroll
        for (int hh = 0; hh < 2; ++hh) {
            f32x4 c = {bs0[hh], bs0[hh], bs0[hh], bs0[hh]};
            c = MFMA16(a0[t], w0hi[hh], c);
            c = MFMA16(a1[t], w0hi[hh], c);
            c = MFMA16(a2[t], w0hi[hh], c);
            c = MFMA16(a0[t], w0lo[hh], c);
            c = MFMA16(a1[t], w0lo[hh], c);       // a2*w0lo dropped (negligible)
            acc[t][hh] = c;
        }
    #pragma unroll
    for (int t = 0; t < 2; ++t)
        #pragma unroll
        for (int hh = 0; hh < 2; ++hh)
            #pragma unroll
            for (int k = 0; k < 4; ++k)
                lds[(t * 16 + quad * 4 + k) * 36 + lm + 16 * hh] =
                    fmaxf(truncf(acc[t][hh][k]), 0.0f);

    // ---------------- layer 1: reload A-layout, 2-chunk split ----------------
    bf16x8 c0f[2], c1f[2];
    #pragma unroll
    for (int t = 0; t < 2; ++t) {
        const int base = (t * 16 + lm) * 36 + quad * 8;
        float4 v0 = *(float4*)&lds[base];
        float4 v1 = *(float4*)&lds[base + 4];
        float h[8] = {v0.x, v0.y, v0.z, v0.w, v1.x, v1.y, v1.z, v1.w};
        #pragma unroll
        for (int j = 0; j < 8; ++j) {
            float c0 = bf_topf(h[j]);
            c0f[t][j] = bf_top(h[j]);
            c1f[t][j] = bf_top(h[j] - c0);        // exact int residue < 256
        }
    }
    #pragma unroll
    for (int t = 0; t < 2; ++t)
        #pragma unroll
        for (int hh = 0; hh < 2; ++hh) {
            f32x4 c = {bs1[hh], bs1[hh], bs1[hh], bs1[hh]};
            c = MFMA16(c0f[t], w1hi[hh], c);
            c = MFMA16(c1f[t], w1hi[hh], c);
            c = MFMA16(c0f[t], w1lo[hh], c);
            c = MFMA16(c1f[t], w1lo[hh], c);
            acc[t][hh] = c;
        }
    #pragma unroll
    for (int t = 0; t < 2; ++t)
        #pragma unroll
        for (int hh = 0; hh < 2; ++hh)
            #pragma unroll
            for (int k = 0; k < 4; ++k)
                lds[(t * 16 + quad * 4 + k) * 36 + lm + 16 * hh] =
                    fmaxf(truncf(acc[t][hh][k]), 0.0f);

    // ---------------- output layer ----------------
    bf16x8 d0f[2], d1f[2];
    #pragma unroll
    for (int t = 0; t < 2; ++t) {
        const int base = (t * 16 + lm) * 36 + quad * 8;
        float4 v0 = *(float4*)&lds[base];
        float4 v1 = *(float4*)&lds[base + 4];
        float h[8] = {v0.x, v0.y, v0.z, v0.w, v1.x, v1.y, v1.z, v1.w};
        #pragma unroll
        for (int j = 0; j < 8; ++j) {
            float c0 = bf_topf(h[j]);
            d0f[t][j] = bf_top(h[j]);
            d1f[t][j] = bf_top(h[j] - c0);
        }
    }
    #pragma unroll
    for (int t = 0; t < 2; ++t) {
        f32x4 c = {bsov, bsov, bsov, bsov};
        c = MFMA16(d0f[t], wof, c);
        c = MFMA16(d1f[t], wof, c);

        float o[4];
        #pragma unroll
        for (int k = 0; k < 4; ++k) {
            float a = c[k];                                   // = xx/256, exact
            o[k] = truncf(a + copysignf(0.5f, a)) * (1.0f / 256.0f);
        }
        const size_t row = rowbase + (size_t)(t * 16 + quad * 4);
        if (lm == 0) {                                        // mu
            *(float4*)(out + row) = make_float4(o[0], o[1], o[2], o[3]);
        }
        if (lm == 1) {                                        // log_scale + scale
            *(float4*)(out + 2 * nn + row) = make_float4(o[0], o[1], o[2], o[3]);
            float s[4];
            #pragma unroll
            for (int k = 0; k < 4; ++k)
                s[k] = expf(fminf(fmaxf(o[k] - 4.0f, -4.6f), 5.0f));
            *(float4*)(out + nn + row) = make_float4(s[0], s[1], s[2], s[3]);
        }
    }
}

extern "C" void kernel_launch(void* const* d_in, const int* in_sizes, int n_in,
                              void* d_out, int out_size, void* d_ws, size_t ws_size,
                              hipStream_t stream) {
    const float* x  = (const float*)d_in[0];
    const float* w0 = (const float*)d_in[1];
    const float* b0 = (const float*)d_in[2];
    const float* w1 = (const float*)d_in[3];
    const float* b1 = (const float*)d_in[4];
    const float* wo = (const float*)d_in[5];
    const float* bo = (const float*)d_in[6];
    float* out = (float*)d_out;

    short* ws  = (short*)d_ws;
    float* bsf = (float*)((char*)d_ws + 10240);

    int nrows = in_sizes[0] / 32;             // B = 2097152, multiple of 128
    int grid = nrows / 128;                   // 128 rows per 256-thread block

    armint_prep<<<1, 256, 0, stream>>>(w0, b0, w1, b1, wo, bo, ws, bsf);
    armint_mfma<<<grid, 256, 0, stream>>>(x, ws, bsf, out, nrows);
}